// Round 1
// baseline (3718.471 us; speedup 1.0000x reference)
//
#include <hip/hip_runtime.h>
#include <math.h>

#define NB    32768
#define DDIM  64
#define HDIM  512
#define PDIM  23      // 3*K - 1
#define KBINS 8
#define BM    16

#define RQ_BOUND  4.0f
#define RQ_MINBIN 0.001f
#define RQ_MINDER 0.001f

// ---------------------------------------------------------------------------
// prep: bake autoregressive masks into weights (closed-form masks, no M1/M2 reads)
//   M1[h,i] = (h%63 + 1 >= i+1)  ->  i <= h%63
//   M2[o,h] = (o/23 + 1 > h%63 + 1) -> (o/23) > h%63
// ---------------------------------------------------------------------------
__global__ __launch_bounds__(256) void prep_masked(const float* __restrict__ W1,
                                                   const float* __restrict__ W2,
                                                   float* __restrict__ W1m,
                                                   float* __restrict__ W2m) {
    int idx = blockIdx.x * 256 + threadIdx.x;
    const int n1 = HDIM * DDIM;          // 32768
    const int n2 = DDIM * PDIM * HDIM;   // 753664
    if (idx < n1) {
        int h = idx >> 6;
        int i = idx & 63;
        W1m[idx] = (i <= (h % 63)) ? W1[idx] : 0.0f;
    } else {
        int j = idx - n1;
        if (j < n2) {
            int o = j >> 9;
            int h = j & 511;
            W2m[j] = ((o / PDIM) > (h % 63)) ? W2[j] : 0.0f;
        }
    }
}

// ---------------------------------------------------------------------------
// monotonic rational-quadratic spline, fully register-resident
// prm[0..7]=w_un  prm[8..15]=h_un  prm[16..22]=d_un
// ---------------------------------------------------------------------------
__device__ __forceinline__ float softplusf(float v) {
    return log1pf(expf(-fabsf(v))) + fmaxf(v, 0.0f);
}

__device__ __forceinline__ void rqs_eval(const float* prm, float xorig,
                                         float& yo, float& ldo) {
    const float xc = fminf(fmaxf(xorig, -RQ_BOUND), RQ_BOUND);
    const bool inside = (xorig >= -RQ_BOUND) && (xorig <= RQ_BOUND);

    float xk[KBINS + 1], yk[KBINS + 1], dd[KBINS + 1];

    // widths -> x knots
    {
        float m = prm[0];
        #pragma unroll
        for (int i = 1; i < KBINS; ++i) m = fmaxf(m, prm[i]);
        float e[KBINS]; float s = 0.0f;
        #pragma unroll
        for (int i = 0; i < KBINS; ++i) { e[i] = expf(prm[i] - m); s += e[i]; }
        const float inv = 1.0f / s;
        float c = 0.0f;
        xk[0] = -RQ_BOUND;
        #pragma unroll
        for (int i = 0; i < KBINS; ++i) {
            float w = RQ_MINBIN + (1.0f - RQ_MINBIN * KBINS) * (e[i] * inv);
            c += w;
            xk[i + 1] = -RQ_BOUND + 2.0f * RQ_BOUND * c;
        }
        xk[KBINS] = RQ_BOUND;   // exact edge, as in reference
    }
    // heights -> y knots
    {
        float m = prm[8];
        #pragma unroll
        for (int i = 1; i < KBINS; ++i) m = fmaxf(m, prm[8 + i]);
        float e[KBINS]; float s = 0.0f;
        #pragma unroll
        for (int i = 0; i < KBINS; ++i) { e[i] = expf(prm[8 + i] - m); s += e[i]; }
        const float inv = 1.0f / s;
        float c = 0.0f;
        yk[0] = -RQ_BOUND;
        #pragma unroll
        for (int i = 0; i < KBINS; ++i) {
            float h = RQ_MINBIN + (1.0f - RQ_MINBIN * KBINS) * (e[i] * inv);
            c += h;
            yk[i + 1] = -RQ_BOUND + 2.0f * RQ_BOUND * c;
        }
        yk[KBINS] = RQ_BOUND;
    }
    // derivatives (9 values, unit endpoints)
    dd[0] = 1.0f;
    #pragma unroll
    for (int i = 0; i < KBINS - 1; ++i) dd[i + 1] = RQ_MINDER + softplusf(prm[16 + i]);
    dd[KBINS] = 1.0f;

    // bin index: count of interior knots <= xc (matches ref's sum(xc>=xk)-1, clipped)
    int idx = 0;
    #pragma unroll
    for (int i = 1; i < KBINS; ++i) idx += (xc >= xk[i]) ? 1 : 0;

    // gather bin-local quantities via cndmask chain (register-only, no scratch)
    float x_k = xk[0], x_k1 = xk[1];
    float y_k = yk[0], y_k1 = yk[1];
    float d_k = dd[0], d_k1 = dd[1];
    #pragma unroll
    for (int i = 1; i < KBINS; ++i) {
        const bool mm = (idx == i);
        x_k  = mm ? xk[i]     : x_k;
        x_k1 = mm ? xk[i + 1] : x_k1;
        y_k  = mm ? yk[i]     : y_k;
        y_k1 = mm ? yk[i + 1] : y_k1;
        d_k  = mm ? dd[i]     : d_k;
        d_k1 = mm ? dd[i + 1] : d_k1;
    }

    const float w_k = x_k1 - x_k;
    const float h_k = y_k1 - y_k;
    const float s   = h_k / w_k;
    const float th  = (xc - x_k) / w_k;
    const float omt = 1.0f - th;
    const float t1m = th * omt;
    const float num = h_k * (s * th * th + d_k * t1m);
    const float den = s + (d_k1 + d_k - 2.0f * s) * t1m;
    const float yin = y_k + num / den;
    const float dnum = s * s * (d_k1 * th * th + 2.0f * s * t1m + d_k * omt * omt);
    const float ldin = logf(dnum) - 2.0f * logf(den);

    yo  = inside ? yin : xorig;
    ldo = inside ? ldin : 0.0f;
}

// ---------------------------------------------------------------------------
// fused: hmid (LDS) -> params (registers) -> spline -> z, logdet
// block = 256 threads (4 waves), BM = 16 rows.
// wave w owns dims d = w*16 + (lane&15); lane group r0 = lane>>4 owns rows
// {r0, r0+4, r0+8, r0+12}. Each lane accumulates 23 params x 4 rows in regs.
// ---------------------------------------------------------------------------
__global__ __launch_bounds__(256) void fused_flow(
    const float* __restrict__ x,  const float* __restrict__ b1,
    const float* __restrict__ b2, const float* __restrict__ W1m,
    const float* __restrict__ W2m, float* __restrict__ z_out,
    float* __restrict__ ld_out)
{
    // pad hm rows by +4 floats: the 4 row-group broadcast reads per ds_read_b128
    // land on distinct bank quads (516 % 32 == 4)
    __shared__ __align__(16) float xs[BM][DDIM];        // 4 KB
    __shared__ __align__(16) float hm[BM][HDIM + 4];    // 33 KB
    __shared__ float ldbuf[BM][4];

    const int t    = threadIdx.x;
    const int row0 = blockIdx.x * BM;

    // ---- load x tile (1024 floats, one float4 per thread, coalesced) ----
    {
        const float4* xg  = reinterpret_cast<const float4*>(x + (size_t)row0 * DDIM);
        float4*       xsv = reinterpret_cast<float4*>(&xs[0][0]);
        xsv[t] = xg[t];
    }
    __syncthreads();

    // ---- phase 1: hmid[16][512] = relu(x @ W1m^T + b1) ----
    for (int e = t; e < BM * HDIM; e += 256) {
        const int r = e >> 9;
        const int h = e & 511;
        const float4* wrow = reinterpret_cast<const float4*>(W1m + h * DDIM);
        const float4* xrow = reinterpret_cast<const float4*>(&xs[r][0]);
        float acc = b1[h];
        #pragma unroll
        for (int i = 0; i < DDIM / 4; ++i) {
            const float4 wv = wrow[i];
            const float4 xv = xrow[i];
            acc += wv.x * xv.x + wv.y * xv.y + wv.z * xv.z + wv.w * xv.w;
        }
        hm[r][h] = fmaxf(acc, 0.0f);
    }
    __syncthreads();

    // ---- phase 2: params = hmid @ W2m^T + b2, 23 params x 4 rows per lane ----
    const int wv   = t >> 6;          // wave 0..3
    const int lane = t & 63;
    const int dl   = lane & 15;
    const int d    = wv * 16 + dl;    // output dim 0..63
    const int r0   = lane >> 4;       // row group 0..3

    float acc[PDIM][4];
    #pragma unroll
    for (int p = 0; p < PDIM; ++p)
        #pragma unroll
        for (int k = 0; k < 4; ++k) acc[p][k] = 0.0f;

    const float4* w2r = reinterpret_cast<const float4*>(W2m + (size_t)d * PDIM * HDIM);
    const float4* h0  = reinterpret_cast<const float4*>(&hm[r0][0]);
    const float4* h1  = reinterpret_cast<const float4*>(&hm[r0 + 4][0]);
    const float4* h2  = reinterpret_cast<const float4*>(&hm[r0 + 8][0]);
    const float4* h3  = reinterpret_cast<const float4*>(&hm[r0 + 12][0]);

    for (int i = 0; i < HDIM / 4; ++i) {
        const float4 v0 = h0[i];
        const float4 v1 = h1[i];
        const float4 v2 = h2[i];
        const float4 v3 = h3[i];
        #pragma unroll
        for (int p = 0; p < PDIM; ++p) {
            const float4 wvv = w2r[p * (HDIM / 4) + i];
            acc[p][0] += wvv.x * v0.x + wvv.y * v0.y + wvv.z * v0.z + wvv.w * v0.w;
            acc[p][1] += wvv.x * v1.x + wvv.y * v1.y + wvv.z * v1.z + wvv.w * v1.w;
            acc[p][2] += wvv.x * v2.x + wvv.y * v2.y + wvv.z * v2.z + wvv.w * v2.w;
            acc[p][3] += wvv.x * v3.x + wvv.y * v3.y + wvv.z * v3.z + wvv.w * v3.w;
        }
    }
    // add bias
    #pragma unroll
    for (int p = 0; p < PDIM; ++p) {
        const float bv = b2[d * PDIM + p];
        #pragma unroll
        for (int k = 0; k < 4; ++k) acc[p][k] += bv;
    }

    // ---- phase 3: spline per (row, dim), then outputs ----
    float ldv[4];
    #pragma unroll
    for (int k = 0; k < 4; ++k) {
        const int r = r0 + 4 * k;
        float prm[PDIM];
        #pragma unroll
        for (int p = 0; p < PDIM; ++p) prm[p] = acc[p][k];
        float yv, lv;
        rqs_eval(prm, xs[r][d], yv, lv);
        z_out[(size_t)(row0 + r) * DDIM + d] = yv;
        ldv[k] = lv;
    }

    // ---- logdet row-sum: 16-lane shfl reduce (dims within wave), LDS across waves
    #pragma unroll
    for (int off = 1; off < 16; off <<= 1) {
        #pragma unroll
        for (int k = 0; k < 4; ++k) ldv[k] += __shfl_xor(ldv[k], off, 64);
    }
    if (dl == 0) {
        #pragma unroll
        for (int k = 0; k < 4; ++k) ldbuf[r0 + 4 * k][wv] = ldv[k];
    }
    __syncthreads();
    if (t < BM) {
        ld_out[row0 + t] = ldbuf[t][0] + ldbuf[t][1] + ldbuf[t][2] + ldbuf[t][3];
    }
}

// ---------------------------------------------------------------------------
extern "C" void kernel_launch(void* const* d_in, const int* in_sizes, int n_in,
                              void* d_out, int out_size, void* d_ws, size_t ws_size,
                              hipStream_t stream) {
    (void)in_sizes; (void)n_in; (void)out_size; (void)ws_size;
    const float* x  = (const float*)d_in[0];
    const float* W1 = (const float*)d_in[1];
    const float* b1 = (const float*)d_in[2];
    const float* W2 = (const float*)d_in[3];
    const float* b2 = (const float*)d_in[4];
    // d_in[5]=M1, d_in[6]=M2 unused: masks are closed-form

    float* W1m = (float*)d_ws;                       // 32768 floats
    float* W2m = W1m + HDIM * DDIM;                  // 753664 floats (total ws ~3.1 MB)
    float* z   = (float*)d_out;                      // [32768, 64]
    float* ld  = z + (size_t)NB * DDIM;              // [32768]

    const int n_prep = HDIM * DDIM + DDIM * PDIM * HDIM;     // 786432
    prep_masked<<<(n_prep + 255) / 256, 256, 0, stream>>>(W1, W2, W1m, W2m);
    fused_flow<<<NB / BM, 256, 0, stream>>>(x, b1, b2, W1m, W2m, z, ld);
}

// Round 3
// 436.081 us; speedup vs baseline: 8.5270x; 8.5270x over previous
//
#include <hip/hip_runtime.h>
#include <math.h>

#define NB    32768
#define DDIM  64
#define HDIM  512
#define PDIM  23        // 3*K - 1
#define KBINS 8
#define BM    32
#define NCOLS (DDIM * PDIM)   // 1472
#define CHUNK 368             // 23 n-tiles of 16 = 16 d's worth of params
#define NT2   23              // tiles per chunk
#define PSTRIDE 372           // f32 per pstage row (368 + pad)

#define RQ_BOUND  4.0f
#define RQ_MINBIN 0.001f
#define RQ_MINDER 0.001f

typedef __attribute__((ext_vector_type(8))) short short8;
typedef __attribute__((ext_vector_type(4))) float f32x4;
typedef unsigned short ushort_t;

__device__ __forceinline__ unsigned short f2bf(float f) {
    unsigned int u = __builtin_bit_cast(unsigned int, f);
    unsigned int r = (u + 0x7FFFu + ((u >> 16) & 1u)) >> 16;
    return (unsigned short)r;
}
__device__ __forceinline__ float bf2f(unsigned short h) {
    unsigned int u = ((unsigned int)h) << 16;
    return __builtin_bit_cast(float, u);
}

// ---------------------------------------------------------------------------
// prep: bake masks, split each weight into bf16 hi + bf16 lo (v - hi exact in f32)
//   M1[h,i] = i <= h%63 ; M2[o,h] = o/23 > h%63
// ---------------------------------------------------------------------------
__global__ __launch_bounds__(256) void prep_split(const float* __restrict__ W1,
                                                  const float* __restrict__ W2,
                                                  ushort_t* __restrict__ W1h,
                                                  ushort_t* __restrict__ W1l,
                                                  ushort_t* __restrict__ W2h,
                                                  ushort_t* __restrict__ W2l) {
    int idx = blockIdx.x * 256 + threadIdx.x;
    const int n1 = HDIM * DDIM;          // 32768
    if (idx < n1) {
        int h = idx >> 6, i = idx & 63;
        float w = (i <= (h % 63)) ? W1[idx] : 0.0f;
        unsigned short hi = f2bf(w);
        W1h[idx] = hi;
        W1l[idx] = f2bf(w - bf2f(hi));
    } else {
        int j = idx - n1;
        if (j < NCOLS * HDIM) {
            int o = j >> 9, hh = j & 511;
            float w = ((o / PDIM) > (hh % 63)) ? W2[j] : 0.0f;
            unsigned short hi = f2bf(w);
            W2h[j] = hi;
            W2l[j] = f2bf(w - bf2f(hi));
        }
    }
}

// ---------------------------------------------------------------------------
// rational-quadratic spline (validated rounds 1-2, f32 throughout)
// ---------------------------------------------------------------------------
__device__ __forceinline__ float softplusf(float v) {
    return log1pf(expf(-fabsf(v))) + fmaxf(v, 0.0f);
}

__device__ __forceinline__ void rqs_eval(const float* prm, float xorig,
                                         float& yo, float& ldo) {
    const float xc = fminf(fmaxf(xorig, -RQ_BOUND), RQ_BOUND);
    const bool inside = (xorig >= -RQ_BOUND) && (xorig <= RQ_BOUND);

    float xk[KBINS + 1], yk[KBINS + 1], dd[KBINS + 1];
    {
        float m = prm[0];
        #pragma unroll
        for (int i = 1; i < KBINS; ++i) m = fmaxf(m, prm[i]);
        float e[KBINS]; float s = 0.0f;
        #pragma unroll
        for (int i = 0; i < KBINS; ++i) { e[i] = expf(prm[i] - m); s += e[i]; }
        const float inv = 1.0f / s;
        float c = 0.0f;
        xk[0] = -RQ_BOUND;
        #pragma unroll
        for (int i = 0; i < KBINS; ++i) {
            float w = RQ_MINBIN + (1.0f - RQ_MINBIN * KBINS) * (e[i] * inv);
            c += w;
            xk[i + 1] = -RQ_BOUND + 2.0f * RQ_BOUND * c;
        }
        xk[KBINS] = RQ_BOUND;
    }
    {
        float m = prm[8];
        #pragma unroll
        for (int i = 1; i < KBINS; ++i) m = fmaxf(m, prm[8 + i]);
        float e[KBINS]; float s = 0.0f;
        #pragma unroll
        for (int i = 0; i < KBINS; ++i) { e[i] = expf(prm[8 + i] - m); s += e[i]; }
        const float inv = 1.0f / s;
        float c = 0.0f;
        yk[0] = -RQ_BOUND;
        #pragma unroll
        for (int i = 0; i < KBINS; ++i) {
            float h = RQ_MINBIN + (1.0f - RQ_MINBIN * KBINS) * (e[i] * inv);
            c += h;
            yk[i + 1] = -RQ_BOUND + 2.0f * RQ_BOUND * c;
        }
        yk[KBINS] = RQ_BOUND;
    }
    dd[0] = 1.0f;
    #pragma unroll
    for (int i = 0; i < KBINS - 1; ++i) dd[i + 1] = RQ_MINDER + softplusf(prm[16 + i]);
    dd[KBINS] = 1.0f;

    int idx = 0;
    #pragma unroll
    for (int i = 1; i < KBINS; ++i) idx += (xc >= xk[i]) ? 1 : 0;

    float x_k = xk[0], x_k1 = xk[1];
    float y_k = yk[0], y_k1 = yk[1];
    float d_k = dd[0], d_k1 = dd[1];
    #pragma unroll
    for (int i = 1; i < KBINS; ++i) {
        const bool mm = (idx == i);
        x_k  = mm ? xk[i]     : x_k;
        x_k1 = mm ? xk[i + 1] : x_k1;
        y_k  = mm ? yk[i]     : y_k;
        y_k1 = mm ? yk[i + 1] : y_k1;
        d_k  = mm ? dd[i]     : d_k;
        d_k1 = mm ? dd[i + 1] : d_k1;
    }

    const float w_k = x_k1 - x_k;
    const float h_k = y_k1 - y_k;
    const float s   = h_k / w_k;
    const float th  = (xc - x_k) / w_k;
    const float omt = 1.0f - th;
    const float t1m = th * omt;
    const float num = h_k * (s * th * th + d_k * t1m);
    const float den = s + (d_k1 + d_k - 2.0f * s) * t1m;
    const float yin = y_k + num / den;
    const float dnum = s * s * (d_k1 * th * th + 2.0f * s * t1m + d_k * omt * omt);
    const float ldin = logf(dnum) - 2.0f * logf(den);

    yo  = inside ? yin : xorig;
    ldo = inside ? ldin : 0.0f;
}

// ---------------------------------------------------------------------------
// fused split-bf16 MFMA kernel: 32 rows/block, 512 threads (8 waves)
// Each wave owns n-col-tiles and computes BOTH 16-row m-tiles (B-frag reuse).
// GEMM1: hmid[32x512] -> relu -> split hi/lo -> swizzled LDS.
// GEMM2: 4 chunks of 368 cols (23 tiles; wave wv owns tiles wv*3..wv*3+2,
//        wave 7 owns 2). f32 acc -> pstage (full chunk) -> spline (512 thr).
// ---------------------------------------------------------------------------
__global__ __launch_bounds__(512) void fused_flow(
    const float* __restrict__ x,  const float* __restrict__ b1,
    const float* __restrict__ b2,
    const ushort_t* __restrict__ W1h, const ushort_t* __restrict__ W1l,
    const ushort_t* __restrict__ W2h, const ushort_t* __restrict__ W2l,
    float* __restrict__ z_out, float* __restrict__ ld_out)
{
    __shared__ __align__(16) ushort_t hmh[BM * 512];   // 32 KB
    __shared__ __align__(16) ushort_t hml[BM * 512];   // 32 KB
    __shared__ __align__(16) ushort_t xh[BM * 64];     //  4 KB
    __shared__ __align__(16) ushort_t xl[BM * 64];     //  4 KB
    __shared__ __align__(16) float pstage[BM * PSTRIDE]; // 46.5 KB
    __shared__ float b1s[HDIM];                        //  2 KB
    __shared__ float b2s[NCOLS];                       //  5.75 KB

    const int t    = threadIdx.x;
    const int row0 = blockIdx.x * BM;
    const int wv   = t >> 6;
    const int lane = t & 63;
    const int l15  = lane & 15;
    const int lg   = lane >> 4;

    char* hmhB = (char*)hmh;
    char* hmlB = (char*)hml;
    char* xhB  = (char*)xh;
    char* xlB  = (char*)xl;

    // ---- phase 0: x tile -> split bf16 swizzled LDS; biases -> LDS ----
    if (t < 256) {
        const int r  = t >> 3;          // 0..31
        const int kc = (t & 7) * 8;     // 0..56
        const float* xr = x + (size_t)(row0 + r) * DDIM + kc;
        short8 vh, vl;
        #pragma unroll
        for (int i = 0; i < 8; ++i) {
            float v = xr[i];
            unsigned short hi = f2bf(v);
            vh[i] = (short)hi;
            vl[i] = (short)f2bf(v - bf2f(hi));
        }
        const int off = (kc * 2) ^ ((r & 7) << 4);
        *(short8*)(xhB + r * 128 + off) = vh;
        *(short8*)(xlB + r * 128 + off) = vl;
    }
    b1s[t] = b1[t];
    for (int i = t; i < NCOLS; i += 512) b2s[i] = b2[i];
    __syncthreads();

    // ---- phase 1: GEMM1 (split, 3 MFMA/tile/kt) -> hm hi/lo ----
    {
        f32x4 acc1[4][2];
        #pragma unroll
        for (int j = 0; j < 4; ++j)
            #pragma unroll
            for (int m = 0; m < 2; ++m) acc1[j][m] = (f32x4){0.f, 0.f, 0.f, 0.f};

        #pragma unroll
        for (int kt = 0; kt < 2; ++kt) {
            short8 ah[2], al[2];
            #pragma unroll
            for (int m = 0; m < 2; ++m) {
                const int r  = m * 16 + l15;
                const int kb = (kt * 32 + lg * 8) * 2;
                const int off = kb ^ ((r & 7) << 4);
                ah[m] = *(const short8*)(xhB + r * 128 + off);
                al[m] = *(const short8*)(xlB + r * 128 + off);
            }
            #pragma unroll
            for (int j = 0; j < 4; ++j) {
                const int h = (wv * 4 + j) * 16 + l15;
                const short8 bh = *(const short8*)(W1h + h * 64 + kt * 32 + lg * 8);
                const short8 bl = *(const short8*)(W1l + h * 64 + kt * 32 + lg * 8);
                #pragma unroll
                for (int m = 0; m < 2; ++m) {
                    acc1[j][m] = __builtin_amdgcn_mfma_f32_16x16x32_bf16(ah[m], bh, acc1[j][m], 0, 0, 0);
                    acc1[j][m] = __builtin_amdgcn_mfma_f32_16x16x32_bf16(ah[m], bl, acc1[j][m], 0, 0, 0);
                    acc1[j][m] = __builtin_amdgcn_mfma_f32_16x16x32_bf16(al[m], bh, acc1[j][m], 0, 0, 0);
                }
            }
        }
        // epilogue: +bias, relu, split hi/lo, store swizzled
        #pragma unroll
        for (int j = 0; j < 4; ++j) {
            const int h = (wv * 4 + j) * 16 + l15;
            const float bias = b1s[h];
            #pragma unroll
            for (int m = 0; m < 2; ++m) {
                #pragma unroll
                for (int q = 0; q < 4; ++q) {
                    const int r = m * 16 + lg * 4 + q;
                    const float v = fmaxf(acc1[j][m][q] + bias, 0.0f);
                    const unsigned short hi = f2bf(v);
                    const unsigned short lo = f2bf(v - bf2f(hi));
                    const int off = (h * 2) ^ ((r & 7) << 4);
                    *(ushort_t*)(hmhB + r * 1024 + off) = hi;
                    *(ushort_t*)(hmlB + r * 1024 + off) = lo;
                }
            }
        }
    }
    __syncthreads();

    // ---- phase 2: GEMM2 (split) + spline, 4 chunks ----
    float ldacc = 0.0f;
    const int srow = t >> 4;   // 0..31
    const int sd   = t & 15;   // 0..15
    const int tbase = wv * 3;
    const int ntl   = (wv == 7) ? 2 : 3;

    for (int c = 0; c < 4; ++c) {
        f32x4 acc[3][2];
        #pragma unroll
        for (int i = 0; i < 3; ++i)
            #pragma unroll
            for (int m = 0; m < 2; ++m) acc[i][m] = (f32x4){0.f, 0.f, 0.f, 0.f};

        for (int kt = 0; kt < 16; ++kt) {
            short8 ah[2], al[2];
            #pragma unroll
            for (int m = 0; m < 2; ++m) {
                const int r  = m * 16 + l15;
                const int kb = (kt * 32 + lg * 8) * 2;
                const int off = kb ^ ((r & 7) << 4);
                ah[m] = *(const short8*)(hmhB + r * 1024 + off);
                al[m] = *(const short8*)(hmlB + r * 1024 + off);
            }
            #pragma unroll
            for (int i = 0; i < 3; ++i) {
                if (i < ntl) {
                    const size_t col = (size_t)(c * CHUNK + (tbase + i) * 16 + l15);
                    const short8 bh = *(const short8*)(W2h + col * HDIM + kt * 32 + lg * 8);
                    const short8 bl = *(const short8*)(W2l + col * HDIM + kt * 32 + lg * 8);
                    #pragma unroll
                    for (int m = 0; m < 2; ++m) {
                        acc[i][m] = __builtin_amdgcn_mfma_f32_16x16x32_bf16(ah[m], bh, acc[i][m], 0, 0, 0);
                        acc[i][m] = __builtin_amdgcn_mfma_f32_16x16x32_bf16(ah[m], bl, acc[i][m], 0, 0, 0);
                        acc[i][m] = __builtin_amdgcn_mfma_f32_16x16x32_bf16(al[m], bh, acc[i][m], 0, 0, 0);
                    }
                }
            }
        }

        // stage full chunk (f32)
        #pragma unroll
        for (int i = 0; i < 3; ++i) {
            if (i < ntl) {
                const int lcol = (tbase + i) * 16 + l15;
                #pragma unroll
                for (int m = 0; m < 2; ++m) {
                    #pragma unroll
                    for (int q = 0; q < 4; ++q) {
                        const int r = m * 16 + lg * 4 + q;
                        pstage[r * PSTRIDE + lcol] = acc[i][m][q];
                    }
                }
            }
        }
        __syncthreads();

        // spline: one (row, d) per thread — 32 rows x 16 d's = 512
        {
            const int d = c * 16 + sd;
            float prm[PDIM];
            #pragma unroll
            for (int p = 0; p < PDIM; ++p)
                prm[p] = pstage[srow * PSTRIDE + sd * PDIM + p] + b2s[d * PDIM + p];
            const float xv = x[(size_t)(row0 + srow) * DDIM + d];
            float yv, lv;
            rqs_eval(prm, xv, yv, lv);
            z_out[(size_t)(row0 + srow) * DDIM + d] = yv;
            ldacc += lv;
        }
        __syncthreads();
    }

    // ---- logdet: sum the 16 threads of each row (consecutive aligned lanes)
    ldacc += __shfl_xor(ldacc, 1, 64);
    ldacc += __shfl_xor(ldacc, 2, 64);
    ldacc += __shfl_xor(ldacc, 4, 64);
    ldacc += __shfl_xor(ldacc, 8, 64);
    if (sd == 0) ld_out[row0 + srow] = ldacc;
}

// ---------------------------------------------------------------------------
extern "C" void kernel_launch(void* const* d_in, const int* in_sizes, int n_in,
                              void* d_out, int out_size, void* d_ws, size_t ws_size,
                              hipStream_t stream) {
    (void)in_sizes; (void)n_in; (void)out_size; (void)ws_size;
    const float* x  = (const float*)d_in[0];
    const float* W1 = (const float*)d_in[1];
    const float* b1 = (const float*)d_in[2];
    const float* W2 = (const float*)d_in[3];
    const float* b2 = (const float*)d_in[4];

    ushort_t* W1h = (ushort_t*)d_ws;                 // 32768 bf16
    ushort_t* W1l = W1h + HDIM * DDIM;               // 32768
    ushort_t* W2h = W1l + HDIM * DDIM;               // 753664
    ushort_t* W2l = W2h + NCOLS * HDIM;              // 753664  (total ~3.1 MB)
    float* z  = (float*)d_out;
    float* ld = z + (size_t)NB * DDIM;

    const int n_prep = HDIM * DDIM + NCOLS * HDIM;   // 786432
    prep_split<<<(n_prep + 255) / 256, 256, 0, stream>>>(W1, W2, W1h, W1l, W2h, W2l);
    fused_flow<<<NB / BM, 512, 0, stream>>>(x, b1, b2, W1h, W1l, W2h, W2l, z, ld);
}

// Round 4
// 209.445 us; speedup vs baseline: 17.7539x; 2.0821x over previous
//
#include <hip/hip_runtime.h>
#include <math.h>

#define NB    32768
#define DDIM  64
#define HDIM  512
#define PDIM  23        // 3*K - 1
#define KBINS 8
#define BM    32
#define NCOLS (DDIM * PDIM)   // 1472
#define CHUNK 368             // 23 n-tiles of 16 = 16 d's worth of params
#define PSTRIDE 372           // f32 per pstage row (368 + pad)

#define RQ_BOUND  4.0f
#define RQ_MINBIN 0.001f
#define RQ_MINDER 0.001f

typedef __attribute__((ext_vector_type(8))) _Float16 half8;
typedef __attribute__((ext_vector_type(4))) float f32x4;
typedef unsigned short ushort_t;

// ---------------------------------------------------------------------------
// prep: bake masks, convert to fp16.  M1[h,i] = i <= h%63 ; M2[o,h] = o/23 > h%63
// ---------------------------------------------------------------------------
__global__ __launch_bounds__(256) void prep_f16(const float* __restrict__ W1,
                                                const float* __restrict__ W2,
                                                _Float16* __restrict__ W1f,
                                                _Float16* __restrict__ W2f) {
    int idx = blockIdx.x * 256 + threadIdx.x;
    const int n1 = HDIM * DDIM;          // 32768
    if (idx < n1) {
        int h = idx >> 6, i = idx & 63;
        W1f[idx] = (_Float16)((i <= (h % 63)) ? W1[idx] : 0.0f);
    } else {
        int j = idx - n1;
        if (j < NCOLS * HDIM) {
            int o = j >> 9, hh = j & 511;
            W2f[j] = (_Float16)(((o / PDIM) > (hh % 63)) ? W2[j] : 0.0f);
        }
    }
}

// ---------------------------------------------------------------------------
// rational-quadratic spline (validated rounds 1-3, f32 throughout)
// ---------------------------------------------------------------------------
__device__ __forceinline__ float softplusf(float v) {
    return log1pf(expf(-fabsf(v))) + fmaxf(v, 0.0f);
}

__device__ __forceinline__ void rqs_eval(const float* prm, float xorig,
                                         float& yo, float& ldo) {
    const float xc = fminf(fmaxf(xorig, -RQ_BOUND), RQ_BOUND);
    const bool inside = (xorig >= -RQ_BOUND) && (xorig <= RQ_BOUND);

    float xk[KBINS + 1], yk[KBINS + 1], dd[KBINS + 1];
    {
        float m = prm[0];
        #pragma unroll
        for (int i = 1; i < KBINS; ++i) m = fmaxf(m, prm[i]);
        float e[KBINS]; float s = 0.0f;
        #pragma unroll
        for (int i = 0; i < KBINS; ++i) { e[i] = expf(prm[i] - m); s += e[i]; }
        const float inv = 1.0f / s;
        float c = 0.0f;
        xk[0] = -RQ_BOUND;
        #pragma unroll
        for (int i = 0; i < KBINS; ++i) {
            float w = RQ_MINBIN + (1.0f - RQ_MINBIN * KBINS) * (e[i] * inv);
            c += w;
            xk[i + 1] = -RQ_BOUND + 2.0f * RQ_BOUND * c;
        }
        xk[KBINS] = RQ_BOUND;
    }
    {
        float m = prm[8];
        #pragma unroll
        for (int i = 1; i < KBINS; ++i) m = fmaxf(m, prm[8 + i]);
        float e[KBINS]; float s = 0.0f;
        #pragma unroll
        for (int i = 0; i < KBINS; ++i) { e[i] = expf(prm[8 + i] - m); s += e[i]; }
        const float inv = 1.0f / s;
        float c = 0.0f;
        yk[0] = -RQ_BOUND;
        #pragma unroll
        for (int i = 0; i < KBINS; ++i) {
            float h = RQ_MINBIN + (1.0f - RQ_MINBIN * KBINS) * (e[i] * inv);
            c += h;
            yk[i + 1] = -RQ_BOUND + 2.0f * RQ_BOUND * c;
        }
        yk[KBINS] = RQ_BOUND;
    }
    dd[0] = 1.0f;
    #pragma unroll
    for (int i = 0; i < KBINS - 1; ++i) dd[i + 1] = RQ_MINDER + softplusf(prm[16 + i]);
    dd[KBINS] = 1.0f;

    int idx = 0;
    #pragma unroll
    for (int i = 1; i < KBINS; ++i) idx += (xc >= xk[i]) ? 1 : 0;

    float x_k = xk[0], x_k1 = xk[1];
    float y_k = yk[0], y_k1 = yk[1];
    float d_k = dd[0], d_k1 = dd[1];
    #pragma unroll
    for (int i = 1; i < KBINS; ++i) {
        const bool mm = (idx == i);
        x_k  = mm ? xk[i]     : x_k;
        x_k1 = mm ? xk[i + 1] : x_k1;
        y_k  = mm ? yk[i]     : y_k;
        y_k1 = mm ? yk[i + 1] : y_k1;
        d_k  = mm ? dd[i]     : d_k;
        d_k1 = mm ? dd[i + 1] : d_k1;
    }

    const float w_k = x_k1 - x_k;
    const float h_k = y_k1 - y_k;
    const float s   = h_k / w_k;
    const float th  = (xc - x_k) / w_k;
    const float omt = 1.0f - th;
    const float t1m = th * omt;
    const float num = h_k * (s * th * th + d_k * t1m);
    const float den = s + (d_k1 + d_k - 2.0f * s) * t1m;
    const float yin = y_k + num / den;
    const float dnum = s * s * (d_k1 * th * th + 2.0f * s * t1m + d_k * omt * omt);
    const float ldin = logf(dnum) - 2.0f * logf(den);

    yo  = inside ? yin : xorig;
    ldo = inside ? ldin : 0.0f;
}

// ---------------------------------------------------------------------------
// fused fp16 MFMA kernel: 32 rows/block, 512 threads (8 waves), 2 blocks/CU
// GEMM1: A(x) from global f32->fp16 in regs, B=W1f; hmid -> fp16 swizzled LDS.
// GEMM2: 4 chunks of 368 cols (23 tiles; wave wv owns tiles wv*3..+2, wave 7
//        duplicates tile 22). f32 acc -> full-chunk pstage -> spline (512 thr).
// No barrier between spline(c) and ktloop(c+1): wave drift overlaps VALU/MFMA.
// ---------------------------------------------------------------------------
__global__ __launch_bounds__(512, 4) void fused_flow(
    const float* __restrict__ x,  const float* __restrict__ b1,
    const float* __restrict__ b2, const _Float16* __restrict__ W1f,
    const _Float16* __restrict__ W2f,
    float* __restrict__ z_out, float* __restrict__ ld_out)
{
    __shared__ __align__(16) ushort_t hm[BM * 512];      // 32 KB fp16, swizzled
    __shared__ __align__(16) float pstage[BM * PSTRIDE]; // 46.5 KB

    const int t    = threadIdx.x;
    const int row0 = blockIdx.x * BM;
    const int wv   = t >> 6;
    const int lane = t & 63;
    const int l15  = lane & 15;
    const int lg   = lane >> 4;

    char* hmB = (char*)hm;

    // ---- phase 1: GEMM1 (x from global, W1f from global) -> hm fp16 ----
    {
        f32x4 acc1[4][2];
        #pragma unroll
        for (int j = 0; j < 4; ++j)
            #pragma unroll
            for (int m = 0; m < 2; ++m) acc1[j][m] = (f32x4){0.f, 0.f, 0.f, 0.f};

        #pragma unroll
        for (int kt = 0; kt < 2; ++kt) {
            half8 a[2];
            #pragma unroll
            for (int m = 0; m < 2; ++m) {
                const float* xr = x + (size_t)(row0 + m * 16 + l15) * DDIM + kt * 32 + lg * 8;
                const float4 xa = *(const float4*)(xr);
                const float4 xb = *(const float4*)(xr + 4);
                a[m][0] = (_Float16)xa.x; a[m][1] = (_Float16)xa.y;
                a[m][2] = (_Float16)xa.z; a[m][3] = (_Float16)xa.w;
                a[m][4] = (_Float16)xb.x; a[m][5] = (_Float16)xb.y;
                a[m][6] = (_Float16)xb.z; a[m][7] = (_Float16)xb.w;
            }
            #pragma unroll
            for (int j = 0; j < 4; ++j) {
                const int h = (wv * 4 + j) * 16 + l15;
                const half8 b = *(const half8*)(W1f + h * 64 + kt * 32 + lg * 8);
                #pragma unroll
                for (int m = 0; m < 2; ++m)
                    acc1[j][m] = __builtin_amdgcn_mfma_f32_16x16x32_f16(a[m], b, acc1[j][m], 0, 0, 0);
            }
        }
        // epilogue: +bias, relu, cvt fp16, store swizzled
        #pragma unroll
        for (int j = 0; j < 4; ++j) {
            const int h = (wv * 4 + j) * 16 + l15;
            const float bias = b1[h];
            #pragma unroll
            for (int m = 0; m < 2; ++m) {
                #pragma unroll
                for (int q = 0; q < 4; ++q) {
                    const int r = m * 16 + lg * 4 + q;
                    const _Float16 hv = (_Float16)fmaxf(acc1[j][m][q] + bias, 0.0f);
                    *(ushort_t*)(hmB + r * 1024 + ((h * 2) ^ ((r & 7) << 4))) =
                        __builtin_bit_cast(ushort_t, hv);
                }
            }
        }
    }
    __syncthreads();

    // ---- phase 2: GEMM2 + spline, 4 chunks ----
    float ldacc = 0.0f;
    const int srow = t >> 4;   // 0..31
    const int sd   = t & 15;   // 0..15
    const int tbase = wv * 3;

    for (int c = 0; c < 4; ++c) {
        f32x4 acc[3][2];
        #pragma unroll
        for (int i = 0; i < 3; ++i)
            #pragma unroll
            for (int m = 0; m < 2; ++m) acc[i][m] = (f32x4){0.f, 0.f, 0.f, 0.f};

        // wave 7's i=2 duplicates tile 22 (discarded at staging) - keeps loop branchless
        const _Float16* w2p[3];
        #pragma unroll
        for (int i = 0; i < 3; ++i) {
            const int tile = (tbase + i < 23) ? (tbase + i) : 22;
            w2p[i] = W2f + (size_t)(c * CHUNK + tile * 16 + l15) * HDIM;
        }

        #pragma unroll 4
        for (int kt = 0; kt < 16; ++kt) {
            half8 ah[2];
            #pragma unroll
            for (int m = 0; m < 2; ++m) {
                const int r  = m * 16 + l15;
                const int kb = (kt * 32 + lg * 8) * 2;
                ah[m] = *(const half8*)(hmB + r * 1024 + (kb ^ ((r & 7) << 4)));
            }
            half8 bfr[3];
            #pragma unroll
            for (int i = 0; i < 3; ++i)
                bfr[i] = *(const half8*)(w2p[i] + kt * 32 + lg * 8);
            #pragma unroll
            for (int i = 0; i < 3; ++i)
                #pragma unroll
                for (int m = 0; m < 2; ++m)
                    acc[i][m] = __builtin_amdgcn_mfma_f32_16x16x32_f16(ah[m], bfr[i], acc[i][m], 0, 0, 0);
        }

        __syncthreads();   // ensure all waves done reading pstage (spline c-1)

        // stage full chunk (f32)
        #pragma unroll
        for (int i = 0; i < 3; ++i) {
            if (tbase + i < 23) {
                const int lcol = (tbase + i) * 16 + l15;
                #pragma unroll
                for (int m = 0; m < 2; ++m)
                    #pragma unroll
                    for (int q = 0; q < 4; ++q)
                        pstage[(m * 16 + lg * 4 + q) * PSTRIDE + lcol] = acc[i][m][q];
            }
        }
        __syncthreads();

        // spline: one (row, d) per thread — 32 rows x 16 d's = 512
        {
            const int d = c * 16 + sd;
            float prm[PDIM];
            #pragma unroll
            for (int p = 0; p < PDIM; ++p)
                prm[p] = pstage[srow * PSTRIDE + sd * PDIM + p] + b2[d * PDIM + p];
            const float xv = x[(size_t)(row0 + srow) * DDIM + d];
            float yv, lv;
            rqs_eval(prm, xv, yv, lv);
            z_out[(size_t)(row0 + srow) * DDIM + d] = yv;
            ldacc += lv;
        }
        // no barrier here: next ktloop doesn't touch pstage; stage(c+1) is
        // protected by the barrier after the next kt-loop.
    }

    // ---- logdet: sum the 16 threads of each row ----
    ldacc += __shfl_xor(ldacc, 1, 64);
    ldacc += __shfl_xor(ldacc, 2, 64);
    ldacc += __shfl_xor(ldacc, 4, 64);
    ldacc += __shfl_xor(ldacc, 8, 64);
    if (sd == 0) ld_out[row0 + srow] = ldacc;
}

// ---------------------------------------------------------------------------
extern "C" void kernel_launch(void* const* d_in, const int* in_sizes, int n_in,
                              void* d_out, int out_size, void* d_ws, size_t ws_size,
                              hipStream_t stream) {
    (void)in_sizes; (void)n_in; (void)out_size; (void)ws_size;
    const float* x  = (const float*)d_in[0];
    const float* W1 = (const float*)d_in[1];
    const float* b1 = (const float*)d_in[2];
    const float* W2 = (const float*)d_in[3];
    const float* b2 = (const float*)d_in[4];

    _Float16* W1f = (_Float16*)d_ws;                 // 32768 fp16
    _Float16* W2f = W1f + HDIM * DDIM;               // 753664 fp16 (total ~1.57 MB)
    float* z  = (float*)d_out;
    float* ld = z + (size_t)NB * DDIM;

    const int n_prep = HDIM * DDIM + NCOLS * HDIM;   // 786432
    prep_f16<<<(n_prep + 255) / 256, 256, 0, stream>>>(W1, W2, W1f, W2f);
    fused_flow<<<NB / BM, 512, 0, stream>>>(x, b1, b2, W1f, W2f, z, ld);
}

// Round 5
// 201.245 us; speedup vs baseline: 18.4774x; 1.0407x over previous
//
#include <hip/hip_runtime.h>
#include <math.h>

#define NB    32768
#define DDIM  64
#define HDIM  512
#define PDIM  23        // 3*K - 1
#define KBINS 8
#define BM    32
#define NCOLS (DDIM * PDIM)   // 1472
#define CHUNK 368             // 23 n-tiles of 16 = 16 d's worth of params
#define PSTRIDE 372           // f32 per pstage row (368 + pad)

#define RQ_BOUND  4.0f
#define RQ_MINBIN 0.001f
#define RQ_MINDER 0.001f

typedef __attribute__((ext_vector_type(8))) _Float16 half8;
typedef __attribute__((ext_vector_type(4))) float f32x4;
typedef unsigned short ushort_t;

// ---------------------------------------------------------------------------
// prep: bake masks, convert to fp16.  M1[h,i] = i <= h%63 ; M2[o,h] = o/23 > h%63
// ---------------------------------------------------------------------------
__global__ __launch_bounds__(256) void prep_f16(const float* __restrict__ W1,
                                                const float* __restrict__ W2,
                                                _Float16* __restrict__ W1f,
                                                _Float16* __restrict__ W2f) {
    int idx = blockIdx.x * 256 + threadIdx.x;
    const int n1 = HDIM * DDIM;          // 32768
    if (idx < n1) {
        int h = idx >> 6, i = idx & 63;
        W1f[idx] = (_Float16)((i <= (h % 63)) ? W1[idx] : 0.0f);
    } else {
        int j = idx - n1;
        if (j < NCOLS * HDIM) {
            int o = j >> 9, hh = j & 511;
            W2f[j] = (_Float16)(((o / PDIM) > (hh % 63)) ? W2[j] : 0.0f);
        }
    }
}

// ---------------------------------------------------------------------------
// fast transcendentals: native v_exp_f32 / v_log_f32 / v_rcp_f32 paths
// (~2 ulp; spline error budget dominated by fp16 GEMM, so negligible here)
// ---------------------------------------------------------------------------
__device__ __forceinline__ float fexp(float v)  { return __expf(v); }
__device__ __forceinline__ float flog(float v)  { return __logf(v); }
__device__ __forceinline__ float fdiv(float a, float b) { return __fdividef(a, b); }

// ---------------------------------------------------------------------------
// rational-quadratic spline (structure validated rounds 1-4; fast-math ops)
// ---------------------------------------------------------------------------
__device__ __forceinline__ void rqs_eval(const float* prm, float xorig,
                                         float& yo, float& ldo) {
    const float xc = fminf(fmaxf(xorig, -RQ_BOUND), RQ_BOUND);
    const bool inside = (xorig >= -RQ_BOUND) && (xorig <= RQ_BOUND);

    float xk[KBINS + 1], yk[KBINS + 1], dd[KBINS + 1];
    {
        float m = prm[0];
        #pragma unroll
        for (int i = 1; i < KBINS; ++i) m = fmaxf(m, prm[i]);
        float e[KBINS]; float s = 0.0f;
        #pragma unroll
        for (int i = 0; i < KBINS; ++i) { e[i] = fexp(prm[i] - m); s += e[i]; }
        const float inv = fdiv(1.0f, s);
        float c = 0.0f;
        xk[0] = -RQ_BOUND;
        #pragma unroll
        for (int i = 0; i < KBINS; ++i) {
            float w = RQ_MINBIN + (1.0f - RQ_MINBIN * KBINS) * (e[i] * inv);
            c += w;
            xk[i + 1] = -RQ_BOUND + 2.0f * RQ_BOUND * c;
        }
        xk[KBINS] = RQ_BOUND;
    }
    {
        float m = prm[8];
        #pragma unroll
        for (int i = 1; i < KBINS; ++i) m = fmaxf(m, prm[8 + i]);
        float e[KBINS]; float s = 0.0f;
        #pragma unroll
        for (int i = 0; i < KBINS; ++i) { e[i] = fexp(prm[8 + i] - m); s += e[i]; }
        const float inv = fdiv(1.0f, s);
        float c = 0.0f;
        yk[0] = -RQ_BOUND;
        #pragma unroll
        for (int i = 0; i < KBINS; ++i) {
            float h = RQ_MINBIN + (1.0f - RQ_MINBIN * KBINS) * (e[i] * inv);
            c += h;
            yk[i + 1] = -RQ_BOUND + 2.0f * RQ_BOUND * c;
        }
        yk[KBINS] = RQ_BOUND;
    }
    // softplus via native exp/log: log1p(e^-|v|) + max(v,0), e in (0,1]
    dd[0] = 1.0f;
    #pragma unroll
    for (int i = 0; i < KBINS - 1; ++i) {
        const float v = prm[16 + i];
        const float e = fexp(-fabsf(v));
        dd[i + 1] = RQ_MINDER + flog(1.0f + e) + fmaxf(v, 0.0f);
    }
    dd[KBINS] = 1.0f;

    int idx = 0;
    #pragma unroll
    for (int i = 1; i < KBINS; ++i) idx += (xc >= xk[i]) ? 1 : 0;

    float x_k = xk[0], x_k1 = xk[1];
    float y_k = yk[0], y_k1 = yk[1];
    float d_k = dd[0], d_k1 = dd[1];
    #pragma unroll
    for (int i = 1; i < KBINS; ++i) {
        const bool mm = (idx == i);
        x_k  = mm ? xk[i]     : x_k;
        x_k1 = mm ? xk[i + 1] : x_k1;
        y_k  = mm ? yk[i]     : y_k;
        y_k1 = mm ? yk[i + 1] : y_k1;
        d_k  = mm ? dd[i]     : d_k;
        d_k1 = mm ? dd[i + 1] : d_k1;
    }

    const float w_k = x_k1 - x_k;
    const float h_k = y_k1 - y_k;
    const float rw  = fdiv(1.0f, w_k);
    const float s   = h_k * rw;
    const float th  = (xc - x_k) * rw;
    const float omt = 1.0f - th;
    const float t1m = th * omt;
    const float num = h_k * (s * th * th + d_k * t1m);
    const float den = s + (d_k1 + d_k - 2.0f * s) * t1m;
    const float yin = y_k + fdiv(num, den);
    const float dnum = s * s * (d_k1 * th * th + 2.0f * s * t1m + d_k * omt * omt);
    const float ldin = flog(dnum) - 2.0f * flog(den);

    yo  = inside ? yin : xorig;
    ldo = inside ? ldin : 0.0f;
}

// ---------------------------------------------------------------------------
// fused fp16 MFMA kernel: 32 rows/block, 512 threads (8 waves), 2 blocks/CU
// GEMM1: A(x) from global f32->fp16 in regs, B=W1f; hmid -> fp16 swizzled LDS.
// GEMM2: 4 chunks of 368 cols (23 tiles; wave wv owns tiles wv*3..+2, wave 7
//        duplicates tile 22). f32 acc -> full-chunk pstage -> spline (512 thr).
// No barrier between spline(c) and ktloop(c+1): wave drift overlaps VALU/MFMA.
// ---------------------------------------------------------------------------
__global__ __launch_bounds__(512, 4) void fused_flow(
    const float* __restrict__ x,  const float* __restrict__ b1,
    const float* __restrict__ b2, const _Float16* __restrict__ W1f,
    const _Float16* __restrict__ W2f,
    float* __restrict__ z_out, float* __restrict__ ld_out)
{
    __shared__ __align__(16) ushort_t hm[BM * 512];      // 32 KB fp16, swizzled
    __shared__ __align__(16) float pstage[BM * PSTRIDE]; // 46.5 KB

    const int t    = threadIdx.x;
    const int row0 = blockIdx.x * BM;
    const int wv   = t >> 6;
    const int lane = t & 63;
    const int l15  = lane & 15;
    const int lg   = lane >> 4;

    char* hmB = (char*)hm;

    // ---- phase 1: GEMM1 (x from global, W1f from global) -> hm fp16 ----
    {
        f32x4 acc1[4][2];
        #pragma unroll
        for (int j = 0; j < 4; ++j)
            #pragma unroll
            for (int m = 0; m < 2; ++m) acc1[j][m] = (f32x4){0.f, 0.f, 0.f, 0.f};

        #pragma unroll
        for (int kt = 0; kt < 2; ++kt) {
            half8 a[2];
            #pragma unroll
            for (int m = 0; m < 2; ++m) {
                const float* xr = x + (size_t)(row0 + m * 16 + l15) * DDIM + kt * 32 + lg * 8;
                const float4 xa = *(const float4*)(xr);
                const float4 xb = *(const float4*)(xr + 4);
                a[m][0] = (_Float16)xa.x; a[m][1] = (_Float16)xa.y;
                a[m][2] = (_Float16)xa.z; a[m][3] = (_Float16)xa.w;
                a[m][4] = (_Float16)xb.x; a[m][5] = (_Float16)xb.y;
                a[m][6] = (_Float16)xb.z; a[m][7] = (_Float16)xb.w;
            }
            #pragma unroll
            for (int j = 0; j < 4; ++j) {
                const int h = (wv * 4 + j) * 16 + l15;
                const half8 b = *(const half8*)(W1f + h * 64 + kt * 32 + lg * 8);
                #pragma unroll
                for (int m = 0; m < 2; ++m)
                    acc1[j][m] = __builtin_amdgcn_mfma_f32_16x16x32_f16(a[m], b, acc1[j][m], 0, 0, 0);
            }
        }
        // epilogue: +bias, relu, cvt fp16, store swizzled
        #pragma unroll
        for (int j = 0; j < 4; ++j) {
            const int h = (wv * 4 + j) * 16 + l15;
            const float bias = b1[h];
            #pragma unroll
            for (int m = 0; m < 2; ++m) {
                #pragma unroll
                for (int q = 0; q < 4; ++q) {
                    const int r = m * 16 + lg * 4 + q;
                    const _Float16 hv = (_Float16)fmaxf(acc1[j][m][q] + bias, 0.0f);
                    *(ushort_t*)(hmB + r * 1024 + ((h * 2) ^ ((r & 7) << 4))) =
                        __builtin_bit_cast(ushort_t, hv);
                }
            }
        }
    }
    __syncthreads();

    // ---- phase 2: GEMM2 + spline, 4 chunks ----
    float ldacc = 0.0f;
    const int srow = t >> 4;   // 0..31
    const int sd   = t & 15;   // 0..15
    const int tbase = wv * 3;

    for (int c = 0; c < 4; ++c) {
        f32x4 acc[3][2];
        #pragma unroll
        for (int i = 0; i < 3; ++i)
            #pragma unroll
            for (int m = 0; m < 2; ++m) acc[i][m] = (f32x4){0.f, 0.f, 0.f, 0.f};

        // wave 7's i=2 duplicates tile 22 (discarded at staging) - keeps loop branchless
        const _Float16* w2p[3];
        #pragma unroll
        for (int i = 0; i < 3; ++i) {
            const int tile = (tbase + i < 23) ? (tbase + i) : 22;
            w2p[i] = W2f + (size_t)(c * CHUNK + tile * 16 + l15) * HDIM;
        }

        #pragma unroll 4
        for (int kt = 0; kt < 16; ++kt) {
            half8 ah[2];
            #pragma unroll
            for (int m = 0; m < 2; ++m) {
                const int r  = m * 16 + l15;
                const int kb = (kt * 32 + lg * 8) * 2;
                ah[m] = *(const half8*)(hmB + r * 1024 + (kb ^ ((r & 7) << 4)));
            }
            half8 bfr[3];
            #pragma unroll
            for (int i = 0; i < 3; ++i)
                bfr[i] = *(const half8*)(w2p[i] + kt * 32 + lg * 8);
            #pragma unroll
            for (int i = 0; i < 3; ++i)
                #pragma unroll
                for (int m = 0; m < 2; ++m)
                    acc[i][m] = __builtin_amdgcn_mfma_f32_16x16x32_f16(ah[m], bfr[i], acc[i][m], 0, 0, 0);
        }

        __syncthreads();   // ensure all waves done reading pstage (spline c-1)

        // stage full chunk (f32)
        #pragma unroll
        for (int i = 0; i < 3; ++i) {
            if (tbase + i < 23) {
                const int lcol = (tbase + i) * 16 + l15;
                #pragma unroll
                for (int m = 0; m < 2; ++m)
                    #pragma unroll
                    for (int q = 0; q < 4; ++q)
                        pstage[(m * 16 + lg * 4 + q) * PSTRIDE + lcol] = acc[i][m][q];
            }
        }
        __syncthreads();

        // spline: one (row, d) per thread — 32 rows x 16 d's = 512
        {
            const int d = c * 16 + sd;
            float prm[PDIM];
            #pragma unroll
            for (int p = 0; p < PDIM; ++p)
                prm[p] = pstage[srow * PSTRIDE + sd * PDIM + p] + b2[d * PDIM + p];
            const float xv = x[(size_t)(row0 + srow) * DDIM + d];
            float yv, lv;
            rqs_eval(prm, xv, yv, lv);
            z_out[(size_t)(row0 + srow) * DDIM + d] = yv;
            ldacc += lv;
        }
        // no barrier here: next ktloop doesn't touch pstage; stage(c+1) is
        // protected by the barrier after the next kt-loop.
    }

    // ---- logdet: sum the 16 threads of each row ----
    ldacc += __shfl_xor(ldacc, 1, 64);
    ldacc += __shfl_xor(ldacc, 2, 64);
    ldacc += __shfl_xor(ldacc, 4, 64);
    ldacc += __shfl_xor(ldacc, 8, 64);
    if (sd == 0) ld_out[row0 + srow] = ldacc;
}

// ---------------------------------------------------------------------------
extern "C" void kernel_launch(void* const* d_in, const int* in_sizes, int n_in,
                              void* d_out, int out_size, void* d_ws, size_t ws_size,
                              hipStream_t stream) {
    (void)in_sizes; (void)n_in; (void)out_size; (void)ws_size;
    const float* x  = (const float*)d_in[0];
    const float* W1 = (const float*)d_in[1];
    const float* b1 = (const float*)d_in[2];
    const float* W2 = (const float*)d_in[3];
    const float* b2 = (const float*)d_in[4];

    _Float16* W1f = (_Float16*)d_ws;                 // 32768 fp16
    _Float16* W2f = W1f + HDIM * DDIM;               // 753664 fp16 (total ~1.57 MB)
    float* z  = (float*)d_out;
    float* ld = z + (size_t)NB * DDIM;

    const int n_prep = HDIM * DDIM + NCOLS * HDIM;   // 786432
    prep_f16<<<(n_prep + 255) / 256, 256, 0, stream>>>(W1, W2, W1f, W2f);
    fused_flow<<<NB / BM, 512, 0, stream>>>(x, b1, b2, W1f, W2f, z, ld);
}